// Round 8
// baseline (354.088 us; speedup 1.0000x reference)
//
#include <hip/hip_runtime.h>
#include <hip/hip_bf16.h>
#include <cstdint>
#include <cstddef>

#define NN    50000
#define FIN   128
#define EE    800000
#define HID_  32
#define HEADS_ 8
#define EMB_  64
#define NEG   0.2f
#define NB_SCAN 196   // ceil(NN/256)
#define LOG2E 1.4426950408889634f

typedef short bf16x8 __attribute__((ext_vector_type(8)));
typedef float f32x4  __attribute__((ext_vector_type(4)));

static __device__ __forceinline__ ushort f2bf(float f){
    uint u = __float_as_uint(f);
    uint r = (u + 0x7FFFu + ((u >> 16) & 1u)) >> 16;   // RNE
    return (ushort)r;
}
static __device__ __forceinline__ float bf2f(ushort u){
    return __uint_as_float(((uint)u) << 16);
}
// p = exp(lrelu(t/LOG2E)) given pre-scaled t: exp2(fmax(t, 0.2t)) via native v_exp_f32
static __device__ __forceinline__ float pexp(float t){
    return __builtin_amdgcn_exp2f(fmaxf(t, NEG * t));
}

// ---------------- fused prep: wt1bf (scaled), wt2 (scaled), w1t, w2t ----------------
__global__ __launch_bounds__(256) void k_prep(const float* __restrict__ Wsrc1, const float* __restrict__ Wdst1,
                                              const float* __restrict__ asrc1, const float* __restrict__ adst1,
                                              const float* __restrict__ Wsrc2, const float* __restrict__ Wdst2,
                                              const float* __restrict__ asrc2, const float* __restrict__ adst2,
                                              ushort* __restrict__ wt1bf, float* __restrict__ wt2,
                                              ushort* __restrict__ w1t, ushort* __restrict__ w2t){
    int idx = blockIdx.x * blockDim.x + threadIdx.x;
    if (idx < 2048){                                   // wt1bf
        int f = idx >> 4, j = idx & 15;
        const float* W; const float* a; int h;
        if (j < 8) { W = Wsrc1; a = asrc1; h = j; } else { W = Wdst1; a = adst1; h = j - 8; }
        float s = 0.f;
        #pragma unroll
        for (int c = 0; c < HID_; ++c)
            s += W[(size_t)f * (HEADS_ * HID_) + h * HID_ + c] * a[h * HID_ + c];
        wt1bf[j * 128 + f] = f2bf(s * LOG2E);
    } else if (idx < 2560){                            // wt2
        int t = idx - 2048;
        int f = t >> 1, j = t & 1;
        const float* W = j ? Wdst2 : Wsrc2;
        const float* a = j ? adst2 : asrc2;
        float s = 0.f;
        #pragma unroll
        for (int c = 0; c < EMB_; ++c) s += W[(size_t)f * EMB_ + c] * a[c];
        wt2[j * 256 + f] = s * LOG2E;
    } else if (idx < 35328){                           // w1t [256][128]
        int t = idx - 2560;
        int n = t >> 7, k = t & 127;
        w1t[t] = f2bf(Wsrc1[(size_t)k * 256 + n]);
    } else if (idx < 51712){                           // w2t [64][256]
        int t = idx - 35328;
        int n = t >> 8, k = t & 255;
        w2t[t] = f2bf(Wsrc2[(size_t)k * 64 + n]);
    }
}

// ---------------- CSR build ----------------
__global__ void k_hist(const int* __restrict__ dst, int* __restrict__ deg, int* __restrict__ rank){
    int e = blockIdx.x * blockDim.x + threadIdx.x;
    if (e < EE) rank[e] = atomicAdd(&deg[dst[e]], 1);
}

// single-kernel scan: all 196 blocks resident; per-lane spin on predecessor flags
__global__ __launch_bounds__(256) void k_scanall(const int* __restrict__ deg, int* __restrict__ row_ptr,
                                                 int* __restrict__ bsum, int* __restrict__ flags){
    __shared__ int s[256];
    __shared__ int ps[256];
    int tid = threadIdx.x, b = blockIdx.x;
    int i = b * 256 + tid;
    int v = (i < NN) ? deg[i] : 0;
    s[tid] = v;
    __syncthreads();
    #pragma unroll
    for (int off = 1; off < 256; off <<= 1){
        int t = (tid >= off) ? s[tid - off] : 0;
        __syncthreads();
        s[tid] += t;
        __syncthreads();
    }
    if (tid == 255){
        bsum[b] = s[255];
        __hip_atomic_store(&flags[b], 1, __ATOMIC_RELEASE, __HIP_MEMORY_SCOPE_AGENT);
    }
    int p = 0;
    if (tid < b){
        while (__hip_atomic_load(&flags[tid], __ATOMIC_ACQUIRE, __HIP_MEMORY_SCOPE_AGENT) == 0){}
        p = bsum[tid];
    }
    ps[tid] = p;
    __syncthreads();
    #pragma unroll
    for (int off = 128; off > 0; off >>= 1){
        if (tid < off) ps[tid] += ps[tid + off];
        __syncthreads();
    }
    int boff = ps[0];
    if (i < NN) row_ptr[i] = boff + s[tid] - v;
    if (b == 0 && tid == 0) row_ptr[NN] = EE;
}

__global__ void k_scatter(const int* __restrict__ src, const int* __restrict__ dst,
                          const int* __restrict__ row_ptr, const int* __restrict__ rank,
                          int* __restrict__ col){
    int e = blockIdx.x * blockDim.x + threadIdx.x;
    if (e < EE){
        int d = dst[e];
        col[row_ptr[d] + rank[e]] = src[e];
    }
}

// ---------------- MFMA bf16 GEMM layer 1 + fused attention scores ----------------
// writes hbf1 SLICED: hb1s[plane][node][32] bf16, plane = col>>5
__global__ __launch_bounds__(256) void k_gemm1_mfma(const float* __restrict__ x,
                                                    const ushort* __restrict__ w1t,   // [256][128] bf16
                                                    const ushort* __restrict__ wt1bf, // [16][128] bf16
                                                    ushort* __restrict__ c,           // sliced [8][NN][32]
                                                    float* __restrict__ a_src1,
                                                    float* __restrict__ a_dst1){
    __shared__ ushort As[64][136];
    __shared__ ushort Bs[128][136];
    __shared__ ushort Bsa[16][136];
    const int tid = threadIdx.x;
    const int m0 = blockIdx.x * 64;
    const int n0 = blockIdx.y * 128;
    #pragma unroll
    for (int i = 0; i < 8; ++i){
        int idx = tid + i * 256;
        int r = idx >> 5, c4 = idx & 31;
        int m = m0 + r;
        float4 v = make_float4(0.f, 0.f, 0.f, 0.f);
        if (m < NN) v = *(const float4*)&x[(size_t)m * FIN + c4 * 4];
        ushort4 u; u.x = f2bf(v.x); u.y = f2bf(v.y); u.z = f2bf(v.z); u.w = f2bf(v.w);
        *(ushort4*)&As[r][c4 * 4] = u;
    }
    #pragma unroll
    for (int i = 0; i < 8; ++i){
        int idx = tid + i * 256;
        int r = idx >> 4, c8 = idx & 15;
        const ushort4* s4 = (const ushort4*)&w1t[(size_t)(n0 + r) * 128 + c8 * 8];
        *(ushort4*)&Bs[r][c8 * 8]     = s4[0];
        *(ushort4*)&Bs[r][c8 * 8 + 4] = s4[1];
    }
    if (blockIdx.y == 0){
        int r = tid >> 4, c8 = tid & 15;
        const ushort4* s4 = (const ushort4*)&wt1bf[r * 128 + c8 * 8];
        *(ushort4*)&Bsa[r][c8 * 8]     = s4[0];
        *(ushort4*)&Bsa[r][c8 * 8 + 4] = s4[1];
    }
    __syncthreads();
    const int lane = tid & 63;
    const int w    = tid >> 6;
    const int mr   = lane & 15;
    const int kg   = lane >> 4;
    f32x4 acc[8];
    #pragma unroll
    for (int i = 0; i < 8; ++i) acc[i] = (f32x4){0.f, 0.f, 0.f, 0.f};
    f32x4 acca = (f32x4){0.f, 0.f, 0.f, 0.f};
    #pragma unroll
    for (int ks = 0; ks < 4; ++ks){
        bf16x8 a = *(const bf16x8*)&As[w * 16 + mr][ks * 32 + kg * 8];
        #pragma unroll
        for (int nf = 0; nf < 8; ++nf){
            bf16x8 b = *(const bf16x8*)&Bs[nf * 16 + mr][ks * 32 + kg * 8];
            acc[nf] = __builtin_amdgcn_mfma_f32_16x16x32_bf16(a, b, acc[nf], 0, 0, 0);
        }
        if (blockIdx.y == 0){
            bf16x8 ba = *(const bf16x8*)&Bsa[mr][ks * 32 + kg * 8];
            acca = __builtin_amdgcn_mfma_f32_16x16x32_bf16(a, ba, acca, 0, 0, 0);
        }
    }
    #pragma unroll
    for (int nf = 0; nf < 8; ++nf){
        int colb = n0 + nf * 16 + mr;
        #pragma unroll
        for (int r = 0; r < 4; ++r){
            int row = m0 + w * 16 + kg * 4 + r;
            if (row < NN)
                c[((size_t)(colb >> 5) * NN + row) * 32 + (colb & 31)] = f2bf(acc[nf][r]);
        }
    }
    if (blockIdx.y == 0){
        int j = mr;
        #pragma unroll
        for (int r = 0; r < 4; ++r){
            int row = m0 + w * 16 + kg * 4 + r;
            if (row < NN){
                if (j < 8) a_src1[(size_t)row * 8 + j]       = acca[r];
                else       a_dst1[(size_t)row * 8 + (j - 8)] = acca[r];
            }
        }
    }
}

// ---------------- MFMA bf16 GEMM layer 2: reads sliced hrel, writes sliced h2 --------
__global__ __launch_bounds__(256) void k_gemm2_mfma(const ushort* __restrict__ hbf,   // sliced [8][NN][32]
                                                    const ushort* __restrict__ w2t,   // [64][256]
                                                    ushort* __restrict__ c2){         // sliced [2][NN][32]
    __shared__ ushort As[64][264];
    __shared__ ushort Bs[64][264];
    const int tid = threadIdx.x;
    const int m0 = blockIdx.x * 64;
    #pragma unroll
    for (int i = 0; i < 8; ++i){
        int idx = tid + i * 256;
        int r = idx >> 5, c8 = idx & 31;    // k = c8*8 = (c8>>2)*32 + (c8&3)*8
        int m = m0 + r;
        ushort4 v0 = make_ushort4(0,0,0,0), v1 = make_ushort4(0,0,0,0);
        if (m < NN){
            const ushort4* s4 = (const ushort4*)&hbf[((size_t)(c8 >> 2) * NN + m) * 32 + (c8 & 3) * 8];
            v0 = s4[0]; v1 = s4[1];
        }
        *(ushort4*)&As[r][c8 * 8]     = v0;
        *(ushort4*)&As[r][c8 * 8 + 4] = v1;
    }
    #pragma unroll
    for (int i = 0; i < 8; ++i){
        int idx = tid + i * 256;
        int r = idx >> 5, c8 = idx & 31;
        const ushort4* s4 = (const ushort4*)&w2t[(size_t)r * 256 + c8 * 8];
        *(ushort4*)&Bs[r][c8 * 8]     = s4[0];
        *(ushort4*)&Bs[r][c8 * 8 + 4] = s4[1];
    }
    __syncthreads();
    const int lane = tid & 63;
    const int w    = tid >> 6;
    const int mr   = lane & 15;
    const int kg   = lane >> 4;
    f32x4 acc[4];
    #pragma unroll
    for (int i = 0; i < 4; ++i) acc[i] = (f32x4){0.f, 0.f, 0.f, 0.f};
    #pragma unroll
    for (int ks = 0; ks < 8; ++ks){
        bf16x8 a = *(const bf16x8*)&As[w * 16 + mr][ks * 32 + kg * 8];
        #pragma unroll
        for (int nf = 0; nf < 4; ++nf){
            bf16x8 b = *(const bf16x8*)&Bs[nf * 16 + mr][ks * 32 + kg * 8];
            acc[nf] = __builtin_amdgcn_mfma_f32_16x16x32_bf16(a, b, acc[nf], 0, 0, 0);
        }
    }
    #pragma unroll
    for (int nf = 0; nf < 4; ++nf){
        int colb = nf * 16 + mr;
        #pragma unroll
        for (int r = 0; r < 4; ++r){
            int row = m0 + w * 16 + kg * 4 + r;
            if (row < NN)
                c2[((size_t)(colb >> 5) * NN + row) * 32 + (colb & 31)] = f2bf(acc[nf][r]);
        }
    }
}

// ---------------- layer-1 aggregation, XCD-plane-sliced ----------------
// plane = blockIdx&7 -> pinned to one XCD (round-robin dispatch); plane slice 3.2MB < 4MB L2.
// wave = one (node, plane); 4 edge slots x 16 lanes x ushort2 (64B/edge slice), 2x unroll.
__global__ __launch_bounds__(256) void k_agg1_s(const ushort* __restrict__ hb1s,  // [8][NN][32]
                                                const float* __restrict__ a_src, const float* __restrict__ a_dst,
                                                const int* __restrict__ row_ptr, const int* __restrict__ col,
                                                const float* __restrict__ b1, const float* __restrict__ wt2,
                                                ushort* __restrict__ hrels,       // [8][NN][32]
                                                float* __restrict__ a_src2, float* __restrict__ a_dst2){
    const int p = blockIdx.x & 7;
    const int node = (blockIdx.x >> 3) * 4 + (threadIdx.x >> 6);
    if (node >= NN) return;
    const int lane = threadIdx.x & 63;
    const int slot = lane >> 4;
    const int c2 = lane & 15;
    const ushort* hp = hb1s + (size_t)p * NN * 32;
    const float ad = a_dst[(size_t)node * 8 + p];
    float acc0 = 0.f, acc1 = 0.f, den = 0.f;
    const int b = row_ptr[node], en = row_ptr[node + 1];
    int i = b;
    for (; i + 8 <= en; i += 8){
        int iA = i + slot, iB = i + 4 + slot;
        int sA = col[iA], sB = col[iB];
        float eA = a_src[(size_t)sA * 8 + p];
        float eB = a_src[(size_t)sB * 8 + p];
        uint uA = *(const uint*)&hp[(size_t)sA * 32 + c2 * 2];
        uint uB = *(const uint*)&hp[(size_t)sB * 32 + c2 * 2];
        float pA = pexp(eA + ad), pB = pexp(eB + ad);
        acc0 += pA * bf2f((ushort)(uA & 0xffff)) + pB * bf2f((ushort)(uB & 0xffff));
        acc1 += pA * bf2f((ushort)(uA >> 16))    + pB * bf2f((ushort)(uB >> 16));
        den  += pA + pB;
    }
    for (; i < en; i += 4){
        int idx = i + slot;
        int s = col[idx < en ? idx : en - 1];
        float e = a_src[(size_t)s * 8 + p];
        uint u = *(const uint*)&hp[(size_t)s * 32 + c2 * 2];
        float pv = (idx < en) ? pexp(e + ad) : 0.f;
        acc0 += pv * bf2f((ushort)(u & 0xffff));
        acc1 += pv * bf2f((ushort)(u >> 16));
        den  += pv;
    }
    // reduce across the 4 edge slots (lane bits 4,5)
    acc0 += __shfl_xor(acc0, 16); acc0 += __shfl_xor(acc0, 32);
    acc1 += __shfl_xor(acc1, 16); acc1 += __shfl_xor(acc1, 32);
    den  += __shfl_xor(den , 16); den  += __shfl_xor(den , 32);
    float inv = 1.f / (den + 1e-16f);
    int ch = p * 32 + c2 * 2;
    float o0 = fmaxf(acc0 * inv + b1[ch],     0.f);
    float o1 = fmaxf(acc1 * inv + b1[ch + 1], 0.f);
    // partial layer-2 scores over this 32-ch slice
    float ps = o0 * wt2[ch]       + o1 * wt2[ch + 1];
    float pd = o0 * wt2[256 + ch] + o1 * wt2[256 + ch + 1];
    #pragma unroll
    for (int off = 1; off < 16; off <<= 1){
        ps += __shfl_xor(ps, off);
        pd += __shfl_xor(pd, off);
    }
    if (lane == 0){
        atomicAdd(&a_src2[node], ps);
        atomicAdd(&a_dst2[node], pd);
    }
    if (lane < 16){
        ushort2 ob; ob.x = f2bf(o0); ob.y = f2bf(o1);
        *(ushort2*)&hrels[((size_t)p * NN + node) * 32 + c2 * 2] = ob;
    }
}

// ---------------- layer-2 aggregation, XCD-plane-sliced (2 planes x 4 XCDs) ----------
__global__ __launch_bounds__(256) void k_agg2_s(const ushort* __restrict__ h2s,   // [2][NN][32]
                                                const float* __restrict__ a_src2, const float* __restrict__ a_dst2,
                                                const int* __restrict__ row_ptr, const int* __restrict__ col,
                                                const float* __restrict__ b2, float* __restrict__ out){
    const int q = blockIdx.x & 7;
    const int p = q >> 2;
    const int node = ((blockIdx.x >> 3) * 4 + (q & 3)) * 4 + (threadIdx.x >> 6);
    if (node >= NN) return;
    const int lane = threadIdx.x & 63;
    const int slot = lane >> 4;
    const int c2 = lane & 15;
    const ushort* hp = h2s + (size_t)p * NN * 32;
    const float ad = a_dst2[node];
    float acc0 = 0.f, acc1 = 0.f, den = 0.f;
    const int b = row_ptr[node], en = row_ptr[node + 1];
    int i = b;
    for (; i + 8 <= en; i += 8){
        int iA = i + slot, iB = i + 4 + slot;
        int sA = col[iA], sB = col[iB];
        float eA = a_src2[sA], eB = a_src2[sB];
        uint uA = *(const uint*)&hp[(size_t)sA * 32 + c2 * 2];
        uint uB = *(const uint*)&hp[(size_t)sB * 32 + c2 * 2];
        float pA = pexp(eA + ad), pB = pexp(eB + ad);
        acc0 += pA * bf2f((ushort)(uA & 0xffff)) + pB * bf2f((ushort)(uB & 0xffff));
        acc1 += pA * bf2f((ushort)(uA >> 16))    + pB * bf2f((ushort)(uB >> 16));
        den  += pA + pB;
    }
    for (; i < en; i += 4){
        int idx = i + slot;
        int s = col[idx < en ? idx : en - 1];
        float e = a_src2[s];
        uint u = *(const uint*)&hp[(size_t)s * 32 + c2 * 2];
        float pv = (idx < en) ? pexp(e + ad) : 0.f;
        acc0 += pv * bf2f((ushort)(u & 0xffff));
        acc1 += pv * bf2f((ushort)(u >> 16));
        den  += pv;
    }
    acc0 += __shfl_xor(acc0, 16); acc0 += __shfl_xor(acc0, 32);
    acc1 += __shfl_xor(acc1, 16); acc1 += __shfl_xor(acc1, 32);
    den  += __shfl_xor(den , 16); den  += __shfl_xor(den , 32);
    float inv = 1.f / (den + 1e-16f);
    if (lane < 16){
        int ch = p * 32 + c2 * 2;
        float2 o;
        o.x = acc0 * inv + b2[ch];
        o.y = acc1 * inv + b2[ch + 1];
        *(float2*)&out[(size_t)node * 64 + ch] = o;
    }
}

// ---------------- host ----------------
extern "C" void kernel_launch(void* const* d_in, const int* in_sizes, int n_in,
                              void* d_out, int out_size, void* d_ws, size_t ws_size,
                              hipStream_t stream){
    const float* x        = (const float*)d_in[0];
    const int*   ei       = (const int*)  d_in[1];
    const float* Wsrc1    = (const float*)d_in[2];
    const float* Wdst1    = (const float*)d_in[3];
    const float* att_src1 = (const float*)d_in[4];
    const float* att_dst1 = (const float*)d_in[5];
    const float* b1       = (const float*)d_in[6];
    const float* Wsrc2    = (const float*)d_in[7];
    const float* Wdst2    = (const float*)d_in[8];
    const float* att_src2 = (const float*)d_in[9];
    const float* att_dst2 = (const float*)d_in[10];
    const float* b2       = (const float*)d_in[11];
    float* out = (float*)d_out;
    const int* srcp = ei;
    const int* dstp = ei + EE;

    char* base = (char*)d_ws;
    ushort* hb1s   = (ushort*)base;  base += (size_t)NN * 256 * 2;   // sliced [8][NN][32]
    ushort* hrels  = (ushort*)base;  base += (size_t)NN * 256 * 2;   // sliced [8][NN][32]
    ushort* h2s    = (ushort*)base;  base += (size_t)NN * 64 * 2;    // sliced [2][NN][32]
    float*  a_src1 = (float*)base;   base += (size_t)NN * 8 * 4;
    float*  a_dst1 = (float*)base;   base += (size_t)NN * 8 * 4;
    ushort* wt1bf  = (ushort*)base;  base += 2048 * 2;
    float*  wt2    = (float*)base;   base += 512 * 4;
    ushort* w1t    = (ushort*)base;  base += 32768 * 2;
    ushort* w2t    = (ushort*)base;  base += 16384 * 2;
    // zero-init region (single memset): deg, flags, a_src2, a_dst2
    int*   deg     = (int*)base;     base += (size_t)NN * 4;
    int*   flags   = (int*)base;     base += 256 * 4;
    float* a_src2  = (float*)base;   base += (size_t)NN * 4;
    float* a_dst2  = (float*)base;   base += (size_t)NN * 4;
    int* row_ptr = (int*)base;       base += (size_t)(NN + 1) * 4;
    int* rank    = (int*)base;       base += (size_t)EE * 4;
    int* col     = (int*)base;       base += (size_t)EE * 4;
    int* bsum    = (int*)base;       base += 256 * 4;

    (void)hipMemsetAsync(deg, 0, (size_t)(NN + 256 + 2 * NN) * sizeof(int), stream);

    k_prep<<<202, 256, 0, stream>>>(Wsrc1, Wdst1, att_src1, att_dst1,
                                    Wsrc2, Wdst2, att_src2, att_dst2,
                                    wt1bf, wt2, w1t, w2t);

    k_hist<<<(EE + 255) / 256, 256, 0, stream>>>(dstp, deg, rank);
    k_scanall<<<NB_SCAN, 256, 0, stream>>>(deg, row_ptr, bsum, flags);
    k_scatter<<<(EE + 255) / 256, 256, 0, stream>>>(srcp, dstp, row_ptr, rank, col);

    dim3 g1((NN + 63) / 64, 2);
    k_gemm1_mfma<<<g1, 256, 0, stream>>>(x, w1t, wt1bf, hb1s, a_src1, a_dst1);

    // 12500 node-blocks x 8 planes; plane = blockIdx & 7 -> one XCD per plane
    k_agg1_s<<<12500 * 8, 256, 0, stream>>>(hb1s, a_src1, a_dst1, row_ptr, col, b1, wt2,
                                            hrels, a_src2, a_dst2);

    k_gemm2_mfma<<<(NN + 63) / 64, 256, 0, stream>>>(hrels, w2t, h2s);

    // 12500 node-blocks x 2 planes (4 XCDs each)
    k_agg2_s<<<3125 * 8, 256, 0, stream>>>(h2s, a_src2, a_dst2, row_ptr, col, b2, out);
}

// Round 9
// 202.711 us; speedup vs baseline: 1.7468x; 1.7468x over previous
//
#include <hip/hip_runtime.h>
#include <hip/hip_bf16.h>
#include <cstdint>
#include <cstddef>

#define NN    50000
#define FIN   128
#define EE    800000
#define HID_  32
#define HEADS_ 8
#define EMB_  64
#define NEG   0.2f
#define NB_SCAN 196    // ceil(NN/256)
#define NB_PREP 202    // 51712/256
#define NB_EDGE 3125   // EE/256
#define NB_GEMM1 1564  // 782*2
#define LOG2E 1.4426950408889634f

typedef short bf16x8 __attribute__((ext_vector_type(8)));
typedef float f32x4  __attribute__((ext_vector_type(4)));

static __device__ __forceinline__ ushort f2bf(float f){
    uint u = __float_as_uint(f);
    uint r = (u + 0x7FFFu + ((u >> 16) & 1u)) >> 16;   // RNE
    return (ushort)r;
}
static __device__ __forceinline__ float bf2f(ushort u){
    return __uint_as_float(((uint)u) << 16);
}
// p = exp(lrelu(t/LOG2E)) for pre-scaled t: exp2(fmax(t, 0.2t)) via native v_exp_f32
static __device__ __forceinline__ float pexp(float t){
    return __builtin_amdgcn_exp2f(fmaxf(t, NEG * t));
}

// ---------------- K1: fused prep (blocks 0..201) + hist (blocks 202..) ----------------
// wt1bf[j][f] 16x128 bf16 scaled LOG2E; wt2[j*256+f] f32 scaled LOG2E;
// w1t [256][128] bf16 = W1^T ; w2t [64][256] bf16 = W2^T
__global__ __launch_bounds__(256) void k_prep_hist(const float* __restrict__ Wsrc1, const float* __restrict__ Wdst1,
                                                   const float* __restrict__ asrc1, const float* __restrict__ adst1,
                                                   const float* __restrict__ Wsrc2, const float* __restrict__ Wdst2,
                                                   const float* __restrict__ asrc2, const float* __restrict__ adst2,
                                                   ushort* __restrict__ wt1bf, float* __restrict__ wt2,
                                                   ushort* __restrict__ w1t, ushort* __restrict__ w2t,
                                                   const int* __restrict__ dst, int* __restrict__ deg,
                                                   int* __restrict__ rank){
    if (blockIdx.x >= NB_PREP){
        int e = (blockIdx.x - NB_PREP) * 256 + threadIdx.x;
        if (e < EE) rank[e] = atomicAdd(&deg[dst[e]], 1);
        return;
    }
    int idx = blockIdx.x * blockDim.x + threadIdx.x;
    if (idx < 2048){                                   // wt1bf
        int f = idx >> 4, j = idx & 15;
        const float* W; const float* a; int h;
        if (j < 8) { W = Wsrc1; a = asrc1; h = j; } else { W = Wdst1; a = adst1; h = j - 8; }
        float s = 0.f;
        #pragma unroll
        for (int c = 0; c < HID_; ++c)
            s += W[(size_t)f * (HEADS_ * HID_) + h * HID_ + c] * a[h * HID_ + c];
        wt1bf[j * 128 + f] = f2bf(s * LOG2E);
    } else if (idx < 2560){                            // wt2
        int t = idx - 2048;
        int f = t >> 1, j = t & 1;
        const float* W = j ? Wdst2 : Wsrc2;
        const float* a = j ? adst2 : asrc2;
        float s = 0.f;
        #pragma unroll
        for (int c = 0; c < EMB_; ++c) s += W[(size_t)f * EMB_ + c] * a[c];
        wt2[j * 256 + f] = s * LOG2E;
    } else if (idx < 35328){                           // w1t [256][128]
        int t = idx - 2560;
        int n = t >> 7, k = t & 127;
        w1t[t] = f2bf(Wsrc1[(size_t)k * 256 + n]);
    } else if (idx < 51712){                           // w2t [64][256]
        int t = idx - 35328;
        int n = t >> 8, k = t & 255;
        w2t[t] = f2bf(Wsrc2[(size_t)k * 64 + n]);
    }
}

// ---------------- K2: single-kernel scan (196 blocks, flag spin) ----------------
__global__ __launch_bounds__(256) void k_scanall(const int* __restrict__ deg, int* __restrict__ row_ptr,
                                                 int* __restrict__ bsum, int* __restrict__ flags){
    __shared__ int s[256];
    __shared__ int ps[256];
    int tid = threadIdx.x, b = blockIdx.x;
    int i = b * 256 + tid;
    int v = (i < NN) ? deg[i] : 0;
    s[tid] = v;
    __syncthreads();
    #pragma unroll
    for (int off = 1; off < 256; off <<= 1){
        int t = (tid >= off) ? s[tid - off] : 0;
        __syncthreads();
        s[tid] += t;
        __syncthreads();
    }
    if (tid == 255){
        bsum[b] = s[255];
        __hip_atomic_store(&flags[b], 1, __ATOMIC_RELEASE, __HIP_MEMORY_SCOPE_AGENT);
    }
    int p = 0;
    if (tid < b){
        while (__hip_atomic_load(&flags[tid], __ATOMIC_ACQUIRE, __HIP_MEMORY_SCOPE_AGENT) == 0){}
        p = bsum[tid];
    }
    ps[tid] = p;
    __syncthreads();
    #pragma unroll
    for (int off = 128; off > 0; off >>= 1){
        if (tid < off) ps[tid] += ps[tid + off];
        __syncthreads();
    }
    int boff = ps[0];
    if (i < NN) row_ptr[i] = boff + s[tid] - v;
    if (b == 0 && tid == 0) row_ptr[NN] = EE;
}

// ---------------- K3: fused gemm1 (blocks 0..1563) + scatter (blocks 1564..) ----------
// gemm1: hbf1[N,256] = bf16(x @ W1), + fused layer-1 scores when n0==0.
__global__ __launch_bounds__(256) void k_gemm1_scatter(const float* __restrict__ x,
                                                       const ushort* __restrict__ w1t,   // [256][128]
                                                       const ushort* __restrict__ wt1bf, // [16][128]
                                                       ushort* __restrict__ c,           // [NN][256] bf16
                                                       float* __restrict__ a_src1,
                                                       float* __restrict__ a_dst1,
                                                       const int* __restrict__ src, const int* __restrict__ dstp,
                                                       const int* __restrict__ row_ptr, const int* __restrict__ rank,
                                                       int* __restrict__ col){
    __shared__ ushort As[64][136];
    __shared__ ushort Bs[128][136];
    __shared__ ushort Bsa[16][136];
    if (blockIdx.x >= NB_GEMM1){
        int e = (blockIdx.x - NB_GEMM1) * 256 + threadIdx.x;
        if (e < EE){
            int d = dstp[e];
            col[row_ptr[d] + rank[e]] = src[e];
        }
        return;
    }
    const int tid = threadIdx.x;
    const int m0 = (blockIdx.x >> 1) * 64;
    const int n0 = (blockIdx.x & 1) * 128;
    #pragma unroll
    for (int i = 0; i < 8; ++i){
        int idx = tid + i * 256;
        int r = idx >> 5, c4 = idx & 31;
        int m = m0 + r;
        float4 v = make_float4(0.f, 0.f, 0.f, 0.f);
        if (m < NN) v = *(const float4*)&x[(size_t)m * FIN + c4 * 4];
        ushort4 u; u.x = f2bf(v.x); u.y = f2bf(v.y); u.z = f2bf(v.z); u.w = f2bf(v.w);
        *(ushort4*)&As[r][c4 * 4] = u;
    }
    #pragma unroll
    for (int i = 0; i < 8; ++i){
        int idx = tid + i * 256;
        int r = idx >> 4, c8 = idx & 15;
        const ushort4* s4 = (const ushort4*)&w1t[(size_t)(n0 + r) * 128 + c8 * 8];
        *(ushort4*)&Bs[r][c8 * 8]     = s4[0];
        *(ushort4*)&Bs[r][c8 * 8 + 4] = s4[1];
    }
    if (n0 == 0){
        int r = tid >> 4, c8 = tid & 15;
        const ushort4* s4 = (const ushort4*)&wt1bf[r * 128 + c8 * 8];
        *(ushort4*)&Bsa[r][c8 * 8]     = s4[0];
        *(ushort4*)&Bsa[r][c8 * 8 + 4] = s4[1];
    }
    __syncthreads();
    const int lane = tid & 63;
    const int w    = tid >> 6;
    const int mr   = lane & 15;
    const int kg   = lane >> 4;
    f32x4 acc[8];
    #pragma unroll
    for (int i = 0; i < 8; ++i) acc[i] = (f32x4){0.f, 0.f, 0.f, 0.f};
    f32x4 acca = (f32x4){0.f, 0.f, 0.f, 0.f};
    #pragma unroll
    for (int ks = 0; ks < 4; ++ks){
        bf16x8 a = *(const bf16x8*)&As[w * 16 + mr][ks * 32 + kg * 8];
        #pragma unroll
        for (int nf = 0; nf < 8; ++nf){
            bf16x8 b = *(const bf16x8*)&Bs[nf * 16 + mr][ks * 32 + kg * 8];
            acc[nf] = __builtin_amdgcn_mfma_f32_16x16x32_bf16(a, b, acc[nf], 0, 0, 0);
        }
        if (n0 == 0){
            bf16x8 ba = *(const bf16x8*)&Bsa[mr][ks * 32 + kg * 8];
            acca = __builtin_amdgcn_mfma_f32_16x16x32_bf16(a, ba, acca, 0, 0, 0);
        }
    }
    #pragma unroll
    for (int nf = 0; nf < 8; ++nf){
        int colb = n0 + nf * 16 + mr;
        #pragma unroll
        for (int r = 0; r < 4; ++r){
            int row = m0 + w * 16 + kg * 4 + r;
            if (row < NN) c[(size_t)row * 256 + colb] = f2bf(acc[nf][r]);
        }
    }
    if (n0 == 0){
        int j = mr;
        #pragma unroll
        for (int r = 0; r < 4; ++r){
            int row = m0 + w * 16 + kg * 4 + r;
            if (row < NN){
                if (j < 8) a_src1[(size_t)row * 8 + j]       = acca[r];
                else       a_dst1[(size_t)row * 8 + (j - 8)] = acca[r];
            }
        }
    }
}

// ---------------- K5: MFMA bf16 GEMM layer 2 ----------------
__global__ __launch_bounds__(256) void k_gemm2_mfma(const ushort* __restrict__ hbf,   // [NN][256]
                                                    const ushort* __restrict__ w2t,   // [64][256]
                                                    ushort* __restrict__ c2){         // [NN][64]
    __shared__ ushort As[64][264];
    __shared__ ushort Bs[64][264];
    const int tid = threadIdx.x;
    const int m0 = blockIdx.x * 64;
    #pragma unroll
    for (int i = 0; i < 8; ++i){
        int idx = tid + i * 256;
        int r = idx >> 5, c8 = idx & 31;
        int m = m0 + r;
        ushort4 v0 = make_ushort4(0,0,0,0), v1 = make_ushort4(0,0,0,0);
        if (m < NN){
            const ushort4* s4 = (const ushort4*)&hbf[(size_t)m * 256 + c8 * 8];
            v0 = s4[0]; v1 = s4[1];
        }
        *(ushort4*)&As[r][c8 * 8]     = v0;
        *(ushort4*)&As[r][c8 * 8 + 4] = v1;
    }
    #pragma unroll
    for (int i = 0; i < 8; ++i){
        int idx = tid + i * 256;
        int r = idx >> 5, c8 = idx & 31;
        const ushort4* s4 = (const ushort4*)&w2t[(size_t)r * 256 + c8 * 8];
        *(ushort4*)&Bs[r][c8 * 8]     = s4[0];
        *(ushort4*)&Bs[r][c8 * 8 + 4] = s4[1];
    }
    __syncthreads();
    const int lane = tid & 63;
    const int w    = tid >> 6;
    const int mr   = lane & 15;
    const int kg   = lane >> 4;
    f32x4 acc[4];
    #pragma unroll
    for (int i = 0; i < 4; ++i) acc[i] = (f32x4){0.f, 0.f, 0.f, 0.f};
    #pragma unroll
    for (int ks = 0; ks < 8; ++ks){
        bf16x8 a = *(const bf16x8*)&As[w * 16 + mr][ks * 32 + kg * 8];
        #pragma unroll
        for (int nf = 0; nf < 4; ++nf){
            bf16x8 b = *(const bf16x8*)&Bs[nf * 16 + mr][ks * 32 + kg * 8];
            acc[nf] = __builtin_amdgcn_mfma_f32_16x16x32_bf16(a, b, acc[nf], 0, 0, 0);
        }
    }
    #pragma unroll
    for (int nf = 0; nf < 4; ++nf){
        int colb = nf * 16 + mr;
        #pragma unroll
        for (int r = 0; r < 4; ++r){
            int row = m0 + w * 16 + kg * 4 + r;
            if (row < NN) c2[(size_t)row * 64 + colb] = f2bf(acc[nf][r]);
        }
    }
}

// ---------------- K4: layer-1 aggregation (wave/node, batch-4) + fused layer-2 scores ----
__global__ __launch_bounds__(256) void k_agg1(const ushort* __restrict__ hsrc, const float* __restrict__ a_src,
                                              const float* __restrict__ a_dst, const int* __restrict__ row_ptr,
                                              const int* __restrict__ col, const float* __restrict__ b1,
                                              const float* __restrict__ wt2,
                                              ushort* __restrict__ hout_bf,
                                              float* __restrict__ a_src2, float* __restrict__ a_dst2){
    int node = blockIdx.x * 4 + (threadIdx.x >> 6);
    if (node >= NN) return;
    int lane = threadIdx.x & 63;
    int head = lane >> 3;
    float ad = a_dst[(size_t)node * 8 + head];
    const ushort4* h4 = (const ushort4*)hsrc;
    float4 acc = make_float4(0.f, 0.f, 0.f, 0.f);
    float den = 0.f;
    int b = row_ptr[node], en = row_ptr[node + 1];
    int i = b;
    for (; i + 4 <= en; i += 4){
        int s0 = col[i], s1 = col[i+1], s2 = col[i+2], s3 = col[i+3];
        float e0 = a_src[(size_t)s0 * 8 + head];
        float e1 = a_src[(size_t)s1 * 8 + head];
        float e2 = a_src[(size_t)s2 * 8 + head];
        float e3 = a_src[(size_t)s3 * 8 + head];
        ushort4 v0 = h4[(size_t)s0 * 64 + lane];
        ushort4 v1 = h4[(size_t)s1 * 64 + lane];
        ushort4 v2 = h4[(size_t)s2 * 64 + lane];
        ushort4 v3 = h4[(size_t)s3 * 64 + lane];
        float p0 = pexp(e0 + ad);
        float p1 = pexp(e1 + ad);
        float p2 = pexp(e2 + ad);
        float p3 = pexp(e3 + ad);
        acc.x += p0*bf2f(v0.x) + p1*bf2f(v1.x) + p2*bf2f(v2.x) + p3*bf2f(v3.x);
        acc.y += p0*bf2f(v0.y) + p1*bf2f(v1.y) + p2*bf2f(v2.y) + p3*bf2f(v3.y);
        acc.z += p0*bf2f(v0.z) + p1*bf2f(v1.z) + p2*bf2f(v2.z) + p3*bf2f(v3.z);
        acc.w += p0*bf2f(v0.w) + p1*bf2f(v1.w) + p2*bf2f(v2.w) + p3*bf2f(v3.w);
        den += p0 + p1 + p2 + p3;
    }
    for (; i < en; ++i){
        int s = col[i];
        float p = pexp(a_src[(size_t)s * 8 + head] + ad);
        ushort4 v = h4[(size_t)s * 64 + lane];
        acc.x += p * bf2f(v.x); acc.y += p * bf2f(v.y);
        acc.z += p * bf2f(v.z); acc.w += p * bf2f(v.w);
        den += p;
    }
    float inv = 1.f / (den + 1e-16f);
    float4 bb = ((const float4*)b1)[lane];
    float4 o;
    o.x = fmaxf(acc.x * inv + bb.x, 0.f);
    o.y = fmaxf(acc.y * inv + bb.y, 0.f);
    o.z = fmaxf(acc.z * inv + bb.z, 0.f);
    o.w = fmaxf(acc.w * inv + bb.w, 0.f);
    ushort4 ob; ob.x = f2bf(o.x); ob.y = f2bf(o.y); ob.z = f2bf(o.z); ob.w = f2bf(o.w);
    ((ushort4*)hout_bf)[(size_t)node * 64 + lane] = ob;
    float4 ws4 = ((const float4*)wt2)[lane];
    float4 wd4 = ((const float4*)(wt2 + 256))[lane];
    float ss2 = o.x*ws4.x + o.y*ws4.y + o.z*ws4.z + o.w*ws4.w;
    float sd2 = o.x*wd4.x + o.y*wd4.y + o.z*wd4.z + o.w*wd4.w;
    #pragma unroll
    for (int off = 32; off > 0; off >>= 1){
        ss2 += __shfl_xor(ss2, off);
        sd2 += __shfl_xor(sd2, off);
    }
    if (lane == 0){ a_src2[node] = ss2; a_dst2[node] = sd2; }
}

// ---------------- K6: layer-2 aggregation (wave/node, batch-4) + bias ----------------
__global__ __launch_bounds__(256) void k_agg2(const ushort* __restrict__ h2bf, const float* __restrict__ a_src2,
                                              const float* __restrict__ a_dst2, const int* __restrict__ row_ptr,
                                              const int* __restrict__ col, const float* __restrict__ b2,
                                              float* __restrict__ out){
    int node = blockIdx.x * 4 + (threadIdx.x >> 6);
    if (node >= NN) return;
    int lane = threadIdx.x & 63;
    float ad = a_dst2[node];
    float acc = 0.f, den = 0.f;
    int b = row_ptr[node], en = row_ptr[node + 1];
    int i = b;
    for (; i + 4 <= en; i += 4){
        int s0 = col[i], s1 = col[i+1], s2 = col[i+2], s3 = col[i+3];
        float e0 = a_src2[s0], e1 = a_src2[s1], e2 = a_src2[s2], e3 = a_src2[s3];
        ushort u0 = h2bf[(size_t)s0 * 64 + lane];
        ushort u1 = h2bf[(size_t)s1 * 64 + lane];
        ushort u2 = h2bf[(size_t)s2 * 64 + lane];
        ushort u3 = h2bf[(size_t)s3 * 64 + lane];
        float p0 = pexp(e0 + ad);
        float p1 = pexp(e1 + ad);
        float p2 = pexp(e2 + ad);
        float p3 = pexp(e3 + ad);
        acc += p0*bf2f(u0) + p1*bf2f(u1) + p2*bf2f(u2) + p3*bf2f(u3);
        den += p0 + p1 + p2 + p3;
    }
    for (; i < en; ++i){
        int s = col[i];
        float p = pexp(a_src2[s] + ad);
        acc += p * bf2f(h2bf[(size_t)s * 64 + lane]);
        den += p;
    }
    out[(size_t)node * 64 + lane] = acc / (den + 1e-16f) + b2[lane];
}

// ---------------- host ----------------
extern "C" void kernel_launch(void* const* d_in, const int* in_sizes, int n_in,
                              void* d_out, int out_size, void* d_ws, size_t ws_size,
                              hipStream_t stream){
    const float* x        = (const float*)d_in[0];
    const int*   ei       = (const int*)  d_in[1];
    const float* Wsrc1    = (const float*)d_in[2];
    const float* Wdst1    = (const float*)d_in[3];
    const float* att_src1 = (const float*)d_in[4];
    const float* att_dst1 = (const float*)d_in[5];
    const float* b1       = (const float*)d_in[6];
    const float* Wsrc2    = (const float*)d_in[7];
    const float* Wdst2    = (const float*)d_in[8];
    const float* att_src2 = (const float*)d_in[9];
    const float* att_dst2 = (const float*)d_in[10];
    const float* b2       = (const float*)d_in[11];
    float* out = (float*)d_out;
    const int* srcp = ei;
    const int* dstp = ei + EE;

    char* base = (char*)d_ws;
    ushort* hbf1   = (ushort*)base;  base += (size_t)NN * 256 * 2;   // h_src1 bf16
    ushort* hrel   = (ushort*)base;  base += (size_t)NN * 256 * 2;   // relu(layer1) bf16
    ushort* h2bf   = (ushort*)base;  base += (size_t)NN * 64 * 2;    // h_src2 bf16
    float*  a_src1 = (float*)base;   base += (size_t)NN * 8 * 4;
    float*  a_dst1 = (float*)base;   base += (size_t)NN * 8 * 4;
    float*  a_src2 = (float*)base;   base += (size_t)NN * 4;
    float*  a_dst2 = (float*)base;   base += (size_t)NN * 4;
    ushort* wt1bf  = (ushort*)base;  base += 2048 * 2;
    float*  wt2    = (float*)base;   base += 512 * 4;
    ushort* w1t    = (ushort*)base;  base += 32768 * 2;
    ushort* w2t    = (ushort*)base;  base += 16384 * 2;
    int* deg     = (int*)base;       base += (size_t)NN * 4;
    int* flags   = (int*)base;       base += 256 * 4;                // adjacent to deg: one memset
    int* row_ptr = (int*)base;       base += (size_t)(NN + 1) * 4;
    int* rank    = (int*)base;       base += (size_t)EE * 4;
    int* col     = (int*)base;       base += (size_t)EE * 4;
    int* bsum    = (int*)base;       base += 256 * 4;

    (void)hipMemsetAsync(deg, 0, (NN + 256) * sizeof(int), stream);  // deg + flags

    // K1: prep || hist
    k_prep_hist<<<NB_PREP + NB_EDGE, 256, 0, stream>>>(Wsrc1, Wdst1, att_src1, att_dst1,
                                                       Wsrc2, Wdst2, att_src2, att_dst2,
                                                       wt1bf, wt2, w1t, w2t,
                                                       dstp, deg, rank);
    // K2: scan
    k_scanall<<<NB_SCAN, 256, 0, stream>>>(deg, row_ptr, bsum, flags);
    // K3: gemm1 || scatter
    k_gemm1_scatter<<<NB_GEMM1 + NB_EDGE, 256, 0, stream>>>(x, w1t, wt1bf, hbf1, a_src1, a_dst1,
                                                            srcp, dstp, row_ptr, rank, col);
    // K4: layer-1 aggregation + fused layer-2 scores
    k_agg1<<<(NN + 3) / 4, 256, 0, stream>>>(hbf1, a_src1, a_dst1, row_ptr, col, b1, wt2,
                                             hrel, a_src2, a_dst2);
    // K5: layer-2 GEMM
    k_gemm2_mfma<<<(NN + 63) / 64, 256, 0, stream>>>(hrel, w2t, h2bf);
    // K6: layer-2 aggregation
    k_agg2<<<(NN + 3) / 4, 256, 0, stream>>>(h2bf, a_src2, a_dst2, row_ptr, col, b2, out);
}